// Round 18
// baseline (265.323 us; speedup 1.0000x reference)
//
#include <hip/hip_runtime.h>
#include <hip/hip_bf16.h>

#define NPIX 4096   // 64*64 pixels per batch
#define CCH  64     // channels
#define NB   8      // batch
#define KVBLK 64    // j-tile per pipeline stage (32KB LDS dbuf)

typedef __attribute__((ext_vector_type(8)))  short short8;   // 8 bf16 MFMA A/B frag (32x32x16)
typedef __attribute__((ext_vector_type(4)))  float f32x4;
typedef __attribute__((ext_vector_type(16))) float f32x16;   // 32x32 MFMA C/D frag

#define LOG2E   1.44269504f

// ---------------------------------------------------------------------------
// Kernel 1: fused 1x1-conv projections, m-split across blocks (R14-proven).
// ---------------------------------------------------------------------------
__global__ __launch_bounds__(256) void proj_kernel(
    const float* __restrict__ x,
    const float* __restrict__ W1, const float* __restrict__ b1,
    const float* __restrict__ W2, const float* __restrict__ b2,
    const float* __restrict__ W3, const float* __restrict__ b3,
    __hip_bfloat16* __restrict__ Q, __hip_bfloat16* __restrict__ G,
    __hip_bfloat16* __restrict__ K)
{
    const int m    = blockIdx.x % 3;
    const int tile = blockIdx.x / 3;
    const int b    = tile >> 6;
    const int i0   = (tile & 63) << 6;

    const float* W  = (m == 0) ? W1 : (m == 1) ? W2 : W3;
    const float* bv = (m == 0) ? b1 : (m == 1) ? b2 : b3;

    __shared__ float xs[64][65];      // xs[c][p]
    __shared__ float Wt[64][68];      // Wt[c][oc]

    for (int e = threadIdx.x; e < 4096; e += 256) {
        const int c = e >> 6, p = e & 63;
        xs[c][p] = x[(size_t)b * CCH * NPIX + (size_t)c * NPIX + i0 + p];
        Wt[e & 63][e >> 6] = W[e];
    }
    __syncthreads();

    const int p = threadIdx.x & 63;
    const int g = threadIdx.x >> 6;

    float acc[16];
    #pragma unroll
    for (int oo = 0; oo < 16; ++oo) acc[oo] = bv[g * 16 + oo];

    for (int c = 0; c < 64; ++c) {
        const float xv = xs[c][p];
        const f32x4* w = (const f32x4*)&Wt[c][g * 16];
        #pragma unroll
        for (int qq = 0; qq < 4; ++qq) {
            const f32x4 a = w[qq];
            #pragma unroll
            for (int j = 0; j < 4; ++j)
                acc[qq * 4 + j] += a[j] * xv;
        }
    }

    const int i = i0 + p;
    if (m == 0) {
        #pragma unroll
        for (int oo = 0; oo < 16; ++oo)
            Q[(size_t)b * NPIX * CCH + (size_t)i * CCH + g * 16 + oo] =
                __float2bfloat16(acc[oo] * LOG2E);
    } else if (m == 1) {
        #pragma unroll
        for (int oo = 0; oo < 16; ++oo)
            G[(size_t)b * NPIX * CCH + (size_t)i * CCH + g * 16 + oo] =
                __float2bfloat16(acc[oo]);
    } else {
        #pragma unroll
        for (int oo = 0; oo < 16; ++oo)
            K[(size_t)b * CCH * NPIX + (size_t)(g * 16 + oo) * NPIX + i] =
                __float2bfloat16(acc[oo]);
    }
}

// ---------------------------------------------------------------------------
// Kernel 2: LDS-staged flash attention, 32x32x16 MFMA, swapped QK^T, KVBLK=64.
// R18 geometry: 4 waves x 64 rows (256 threads). Budget re-audit showed the
// LDS read pipe is the top consumer (~55% of wall incl. conflicts) and the
// 8-wave design read each ga/ka fragment 8x redundantly (fragments depend
// only on lane). 64 rows/wave -> each ds_read feeds 2 MFMAs -> per-CU LDS
// read issue halves (4096->2048 b128/CU). Same MFMA + VALU totals; VGPR
// ~104 (R10-measured) with launch_bounds(256,4) cap 128 -> 4 blocks/CU,
// 4 waves/SIMD (same residency as R14).
// R14-proven paths kept: dbuf + __syncthreads, builtin exp2f pack chain,
// ps VALU row-sum, split=8. Only permlane stays asm.
// 32x32x16 bf16 layouts (m74/m101-verified C/D; A/B contiguous-8k):
//   A: row=lane&31, k=8*(lane>>5)+t     B: col=lane&31, k=8*(lane>>5)+t
//   C/D: col=lane&31, row=(r&3)+8*(r>>2)+4*(lane>>5)
// LDS per buf: G[64 rows][128B] swz ^(row&7)<<4, K[64 c-rows][128B] same.
// ---------------------------------------------------------------------------
__device__ __forceinline__ void gload_lds16(const void* g, void* l) {
    __builtin_amdgcn_global_load_lds(
        (const __attribute__((address_space(1))) unsigned int*)g,
        (__attribute__((address_space(3))) unsigned int*)l, 16, 0, 0);
}
__device__ __forceinline__ unsigned int pack_bf16(float lo, float hi) {
    union { __hip_bfloat162 h; unsigned int u; } w;
    w.h = __float22bfloat162_rn(make_float2(lo, hi));
    return w.u;
}

__global__ __launch_bounds__(256, 4) void attn_kernel(
    const __hip_bfloat16* __restrict__ Qg, const __hip_bfloat16* __restrict__ Gg,
    const __hip_bfloat16* __restrict__ Kg,
    __hip_bfloat16* __restrict__ Opart, float* __restrict__ Lpart, int split)
{
    __shared__ char lds[2][16384];      // [buf][ G 8KB | K 8KB ], XOR-swizzled

    const int blk   = blockIdx.x;
    const int per_b = 16 * split;
    const int b     = blk / per_b;
    const int rem   = blk - b * per_b;
    const int itile = rem / split;
    const int sp    = rem - itile * split;
    const int tid   = threadIdx.x;
    const int wave  = tid >> 6;                   // 0..3
    const int lane  = tid & 63;
    const int l32   = lane & 31;
    const int hi    = lane >> 5;
    const int i0w   = itile * 256 + wave * 64;    // wave's first of 64 rows
    const int jcnt  = NPIX / split;
    const int jlo   = sp * jcnt;
    const int niter = jcnt / KVBLK;

    const short* Qb = (const short*)Qg + (size_t)b * NPIX * CCH;
    const char*  Gb = (const char*)(Gg + (size_t)b * NPIX * CCH);
    const char*  Kb = (const char*)(Kg + (size_t)b * CCH * NPIX);

    // Q B-frags: q[ib][ks] -> Q[i0w+ib*32+l32][16ks+8hi+t]
    short8 q[2][4];
    #pragma unroll
    for (int ib = 0; ib < 2; ++ib)
        #pragma unroll
        for (int ks = 0; ks < 4; ++ks)
            q[ib][ks] = *(const short8*)(Qb + (size_t)(i0w + ib * 32 + l32) * CCH + ks * 16 + hi * 8);

    // hoisted per-lane LDS read bases; per-read addr = base ^ (slot<<4), slot=2ks+hi
    int gbase[2], kbase[2];
    #pragma unroll
    for (int jb = 0; jb < 2; ++jb)
        gbase[jb] = (jb * 32 + l32) * 128 + ((l32 & 7) << 4);
    #pragma unroll
    for (int cb = 0; cb < 2; ++cb)
        kbase[cb] = 8192 + (cb * 32 + l32) * 128 + ((l32 & 7) << 4);

    // hoisted per-lane staging source pointers (256 threads, 2 x 16B per half)
    const char* gsrc[2]; const char* ksrc[2];
    #pragma unroll
    for (int r = 0; r < 2; ++r) {
        const int off = r * 4096 + wave * 1024 + lane * 16;
        const int row = off >> 7, colb = off & 127;
        gsrc[r] = Gb + (size_t)(jlo + row) * 128 + (colb ^ ((row & 7) << 4));
        ksrc[r] = Kb + (size_t)row * 8192 + (size_t)jlo * 2 + (colb ^ ((row & 7) << 4));
    }

    f32x16 zacc;
    #pragma unroll
    for (int r = 0; r < 16; ++r) zacc[r] = 0.f;

    f32x16 o[2][2];                      // [ib][cb] O^T accumulators (64 rows x 64 ch)
    #pragma unroll
    for (int ib = 0; ib < 2; ++ib)
        #pragma unroll
        for (int cb = 0; cb < 2; ++cb)
            #pragma unroll
            for (int r = 0; r < 16; ++r) o[ib][cb][r] = 0.f;
    float ps[2] = {0.f, 0.f};            // per-lane denominator partials (i = lane&31)

    auto STAGE = [&](int buf, int tt) {
        #pragma unroll
        for (int r = 0; r < 2; ++r)
            gload_lds16(gsrc[r] + tt * (KVBLK * 128), lds[buf] + r * 4096 + wave * 1024);
        #pragma unroll
        for (int r = 0; r < 2; ++r)
            gload_lds16(ksrc[r] + tt * (KVBLK * 2), lds[buf] + 8192 + r * 4096 + wave * 1024);
    };

    STAGE(0, 0);
    __syncthreads();

    for (int t = 0; t < niter; ++t) {
        const int cur = t & 1;
        STAGE(cur ^ 1, (t + 1 < niter) ? t + 1 : 0);   // uniform (tail re-stages tile 0)
        const char* L = lds[cur];

        #pragma unroll
        for (int jb = 0; jb < 2; ++jb) {
            short8 ga[4];
            #pragma unroll
            for (int ks = 0; ks < 4; ++ks)
                ga[ks] = *(const short8*)(L + (gbase[jb] ^ ((2 * ks + hi) << 4)));

            short8 pf[2][2];             // [ib][kk]
            #pragma unroll
            for (int ib = 0; ib < 2; ++ib) {
                __builtin_amdgcn_s_setprio(1);
                f32x16 acc = __builtin_amdgcn_mfma_f32_32x32x16_bf16(ga[0], q[ib][0], zacc, 0, 0, 0);
                acc = __builtin_amdgcn_mfma_f32_32x32x16_bf16(ga[1], q[ib][1], acc, 0, 0, 0);
                acc = __builtin_amdgcn_mfma_f32_32x32x16_bf16(ga[2], q[ib][2], acc, 0, 0, 0);
                acc = __builtin_amdgcn_mfma_f32_32x32x16_bf16(ga[3], q[ib][3], acc, 0, 0, 0);
                __builtin_amdgcn_s_setprio(0);

                float p[16];
                #pragma unroll
                for (int r = 0; r < 16; ++r) {
                    p[r] = __builtin_amdgcn_exp2f(acc[r]);
                    ps[ib] += p[r];
                }
                // pack: p[r] holds j_local=(r&3)+8*(r>>2)+4hi; PV B-frag needs
                // lane(hi) to hold j=16kk'+8hi+t. cvt_pk pairs + permlane32_swap (T12).
                #pragma unroll
                for (int kk = 0; kk < 2; ++kk) {
                    unsigned int x0 = pack_bf16(p[8 * kk + 0], p[8 * kk + 1]);
                    unsigned int x1 = pack_bf16(p[8 * kk + 2], p[8 * kk + 3]);
                    unsigned int y0 = pack_bf16(p[8 * kk + 4], p[8 * kk + 5]);
                    unsigned int y1 = pack_bf16(p[8 * kk + 6], p[8 * kk + 7]);
                    asm("v_permlane32_swap_b32 %0, %1" : "+v"(x0), "+v"(y0));
                    asm("v_permlane32_swap_b32 %0, %1" : "+v"(x1), "+v"(y1));
                    union { unsigned int u[4]; short8 v; } w;
                    w.u[0] = x0; w.u[1] = x1; w.u[2] = y0; w.u[3] = y1;
                    pf[ib][kk] = w.v;
                }
            }

            // PV for this jb's two k-slices (ksg = 2jb+kk); ka read ONCE per kk,cb
            __builtin_amdgcn_s_setprio(1);
            #pragma unroll
            for (int kk = 0; kk < 2; ++kk) {
                const int ksg = 2 * jb + kk;
                const short8 ka0 = *(const short8*)(L + (kbase[0] ^ ((2 * ksg + hi) << 4)));
                const short8 ka1 = *(const short8*)(L + (kbase[1] ^ ((2 * ksg + hi) << 4)));
                #pragma unroll
                for (int ib = 0; ib < 2; ++ib) {
                    o[ib][0] = __builtin_amdgcn_mfma_f32_32x32x16_bf16(ka0, pf[ib][kk], o[ib][0], 0, 0, 0);
                    o[ib][1] = __builtin_amdgcn_mfma_f32_32x32x16_bf16(ka1, pf[ib][kk], o[ib][1], 0, 0, 0);
                }
            }
            __builtin_amdgcn_s_setprio(0);
        }
        __syncthreads();   // drains staging vmcnt + all waves done reading cur
    }

    // epilogue: O^T is channel-major -> coalesced bf16 stores
    const size_t pb = (size_t)(b * split + sp);
    #pragma unroll
    for (int ib = 0; ib < 2; ++ib) {
        #pragma unroll
        for (int cb = 0; cb < 2; ++cb)
            #pragma unroll
            for (int r = 0; r < 16; ++r) {
                const int c = cb * 32 + (r & 3) + 8 * (r >> 2) + 4 * hi;
                const int i = i0w + ib * 32 + l32;
                Opart[(pb * CCH + c) * NPIX + i] = __float2bfloat16(o[ib][cb][r]);
            }
        ps[ib] += __shfl_xor(ps[ib], 32);
        if (lane < 32)
            Lpart[pb * NPIX + i0w + ib * 32 + l32] = ps[ib];
    }
}

// ---------------------------------------------------------------------------
// Kernel 3: combine, stripe form (R17-neutral, kept). Block = (b, 64-pixel
// stripe), all 64 channels. Lpart reduced once into LDS invL.
// ---------------------------------------------------------------------------
__global__ __launch_bounds__(256) void combine_kernel(
    const __hip_bfloat16* __restrict__ Opart, const float* __restrict__ Lpart,
    const float* __restrict__ x, float* __restrict__ out, int split)
{
    const int b  = blockIdx.x >> 6;
    const int i0 = (blockIdx.x & 63) << 6;

    __shared__ float invL[64];
    if (threadIdx.x < 64) {
        const int i = i0 + threadIdx.x;
        float L = 0.f;
        for (int s = 0; s < split; ++s)
            L += Lpart[((size_t)(b * split + s)) * NPIX + i];
        invL[threadIdx.x] = 1.0f / L;
    }
    __syncthreads();

    const int c    = threadIdx.x >> 2;        // 0..63
    const int ioff = (threadIdx.x & 3) * 16;  // 16 pixels per thread

    float acc[16];
    #pragma unroll
    for (int k = 0; k < 16; ++k) acc[k] = 0.f;

    for (int s = 0; s < split; ++s) {
        const size_t base = (((size_t)(b * split + s)) * CCH + c) * NPIX + i0 + ioff;
        const short8 v0 = *(const short8*)((const short*)Opart + base);
        const short8 v1 = *(const short8*)((const short*)Opart + base + 8);
        #pragma unroll
        for (int k = 0; k < 8; ++k) {
            union { unsigned int u; float f; } cv0, cv1;
            cv0.u = ((unsigned int)(unsigned short)v0[k]) << 16;
            cv1.u = ((unsigned int)(unsigned short)v1[k]) << 16;
            acc[k]     += cv0.f;
            acc[k + 8] += cv1.f;
        }
    }

    const size_t idx = ((size_t)b * CCH + c) * NPIX + i0 + ioff;
    #pragma unroll
    for (int kq = 0; kq < 4; ++kq) {
        const f32x4 xv = *(const f32x4*)&x[idx + 4 * kq];
        f32x4 r;
        #pragma unroll
        for (int t = 0; t < 4; ++t)
            r[t] = acc[kq * 4 + t] * invL[ioff + kq * 4 + t] + xv[t];
        *(f32x4*)&out[idx + 4 * kq] = r;
    }
}

extern "C" void kernel_launch(void* const* d_in, const int* in_sizes, int n_in,
                              void* d_out, int out_size, void* d_ws, size_t ws_size,
                              hipStream_t stream) {
    const float* x  = (const float*)d_in[0];
    const float* W1 = (const float*)d_in[1];
    const float* b1 = (const float*)d_in[2];
    const float* W2 = (const float*)d_in[3];
    const float* b2 = (const float*)d_in[4];
    const float* W3 = (const float*)d_in[5];
    const float* b3 = (const float*)d_in[6];
    float* out = (float*)d_out;

    char* ws = (char*)d_ws;
    const size_t planeB = (size_t)NB * NPIX * CCH * sizeof(__hip_bfloat16); // 4 MB
    __hip_bfloat16* Q = (__hip_bfloat16*)(ws);
    __hip_bfloat16* G = (__hip_bfloat16*)(ws + planeB);
    __hip_bfloat16* K = (__hip_bfloat16*)(ws + 2 * planeB);

    const size_t base   = 3 * planeB;                               // 12 MB
    const size_t oPlane = planeB;                                   // 4 MB per split (bf16)
    const size_t lPlane = (size_t)NB * NPIX * sizeof(float);        // 128 KB per split

    // prefer split=8 (1024 blocks = 4/CU); fall back if ws is tight
    int split = 8;
    while (split > 1 && base + (size_t)split * (oPlane + lPlane) > ws_size)
        split >>= 1;

    __hip_bfloat16* Opart = (__hip_bfloat16*)(ws + base);
    float* Lpart = (float*)(ws + base + (size_t)split * oPlane);

    proj_kernel<<<dim3(NB * 64 * 3), dim3(256), 0, stream>>>(x, W1, b1, W2, b2, W3, b3, Q, G, K);
    attn_kernel<<<dim3(NB * 16 * split), dim3(256), 0, stream>>>(Q, G, K, Opart, Lpart, split);
    combine_kernel<<<dim3(NB * 64), dim3(256), 0, stream>>>(Opart, Lpart, x, out, split);
}

// Round 19
// 82.938 us; speedup vs baseline: 3.1990x; 3.1990x over previous
//
#include <hip/hip_runtime.h>
#include <hip/hip_bf16.h>

#define NPIX 4096   // 64*64 pixels per batch
#define CCH  64     // channels
#define NB   8      // batch
#define KVBLK 64    // j-tile per pipeline stage (32KB LDS dbuf)

typedef __attribute__((ext_vector_type(8)))  short short8;   // 8 bf16 MFMA A/B frag (32x32x16)
typedef __attribute__((ext_vector_type(4)))  float f32x4;
typedef __attribute__((ext_vector_type(16))) float f32x16;   // 32x32 MFMA C/D frag

#define LOG2E   1.44269504f

// ---------------------------------------------------------------------------
// Kernel 1: fused 1x1-conv projections, m-split across blocks (R14-proven).
// ---------------------------------------------------------------------------
__global__ __launch_bounds__(256) void proj_kernel(
    const float* __restrict__ x,
    const float* __restrict__ W1, const float* __restrict__ b1,
    const float* __restrict__ W2, const float* __restrict__ b2,
    const float* __restrict__ W3, const float* __restrict__ b3,
    __hip_bfloat16* __restrict__ Q, __hip_bfloat16* __restrict__ G,
    __hip_bfloat16* __restrict__ K)
{
    const int m    = blockIdx.x % 3;
    const int tile = blockIdx.x / 3;
    const int b    = tile >> 6;
    const int i0   = (tile & 63) << 6;

    const float* W  = (m == 0) ? W1 : (m == 1) ? W2 : W3;
    const float* bv = (m == 0) ? b1 : (m == 1) ? b2 : b3;

    __shared__ float xs[64][65];      // xs[c][p]
    __shared__ float Wt[64][68];      // Wt[c][oc]

    for (int e = threadIdx.x; e < 4096; e += 256) {
        const int c = e >> 6, p = e & 63;
        xs[c][p] = x[(size_t)b * CCH * NPIX + (size_t)c * NPIX + i0 + p];
        Wt[e & 63][e >> 6] = W[e];
    }
    __syncthreads();

    const int p = threadIdx.x & 63;
    const int g = threadIdx.x >> 6;

    float acc[16];
    #pragma unroll
    for (int oo = 0; oo < 16; ++oo) acc[oo] = bv[g * 16 + oo];

    for (int c = 0; c < 64; ++c) {
        const float xv = xs[c][p];
        const f32x4* w = (const f32x4*)&Wt[c][g * 16];
        #pragma unroll
        for (int qq = 0; qq < 4; ++qq) {
            const f32x4 a = w[qq];
            #pragma unroll
            for (int j = 0; j < 4; ++j)
                acc[qq * 4 + j] += a[j] * xv;
        }
    }

    const int i = i0 + p;
    if (m == 0) {
        #pragma unroll
        for (int oo = 0; oo < 16; ++oo)
            Q[(size_t)b * NPIX * CCH + (size_t)i * CCH + g * 16 + oo] =
                __float2bfloat16(acc[oo] * LOG2E);
    } else if (m == 1) {
        #pragma unroll
        for (int oo = 0; oo < 16; ++oo)
            G[(size_t)b * NPIX * CCH + (size_t)i * CCH + g * 16 + oo] =
                __float2bfloat16(acc[oo]);
    } else {
        #pragma unroll
        for (int oo = 0; oo < 16; ++oo)
            K[(size_t)b * CCH * NPIX + (size_t)(g * 16 + oo) * NPIX + i] =
                __float2bfloat16(acc[oo]);
    }
}

// ---------------------------------------------------------------------------
// Kernel 2: LDS-staged flash attention — R14-proven best (48.5us, VGPR 52).
// 8 waves x 32 rows (512 threads), 4 waves/SIMD. KVBLK=64 dbuf+syncthreads.
// R18's 4-wave LDS-dedup variant spilled (VGPR squeezed 130->64, 500MB
// scratch traffic, 5x slower) — reverted permanently.
// Compiler-visible exp->pack chain (builtin exp2f + __float22bfloat162_rn);
// only permlane stays asm. ps VALU row-sum.
// 32x32x16 bf16 layouts (m74/m101-verified C/D; A/B contiguous-8k):
//   A: row=lane&31, k=8*(lane>>5)+t     B: col=lane&31, k=8*(lane>>5)+t
//   C/D: col=lane&31, row=(r&3)+8*(r>>2)+4*(lane>>5)
// LDS per buf: G[64 rows][128B] swz ^(row&7)<<4, K[64 c-rows][128B] same.
// ---------------------------------------------------------------------------
__device__ __forceinline__ void gload_lds16(const void* g, void* l) {
    __builtin_amdgcn_global_load_lds(
        (const __attribute__((address_space(1))) unsigned int*)g,
        (__attribute__((address_space(3))) unsigned int*)l, 16, 0, 0);
}
__device__ __forceinline__ unsigned int pack_bf16(float lo, float hi) {
    union { __hip_bfloat162 h; unsigned int u; } w;
    w.h = __float22bfloat162_rn(make_float2(lo, hi));
    return w.u;
}

__global__ __launch_bounds__(512, 4) void attn_kernel(
    const __hip_bfloat16* __restrict__ Qg, const __hip_bfloat16* __restrict__ Gg,
    const __hip_bfloat16* __restrict__ Kg,
    __hip_bfloat16* __restrict__ Opart, float* __restrict__ Lpart, int split)
{
    __shared__ char lds[2][16384];      // [buf][ G 8KB | K 8KB ], XOR-swizzled

    const int blk   = blockIdx.x;
    const int per_b = 16 * split;
    const int b     = blk / per_b;
    const int rem   = blk - b * per_b;
    const int itile = rem / split;
    const int sp    = rem - itile * split;
    const int tid   = threadIdx.x;
    const int wave  = tid >> 6;                   // 0..7
    const int lane  = tid & 63;
    const int l32   = lane & 31;
    const int hi    = lane >> 5;
    const int i0w   = itile * 256 + wave * 32;    // wave's first of 32 rows
    const int jcnt  = NPIX / split;
    const int jlo   = sp * jcnt;
    const int niter = jcnt / KVBLK;

    const short* Qb = (const short*)Qg + (size_t)b * NPIX * CCH;
    const char*  Gb = (const char*)(Gg + (size_t)b * NPIX * CCH);
    const char*  Kb = (const char*)(Kg + (size_t)b * CCH * NPIX);

    // Q B-frags: q[ks] -> Q[i0w+l32][16ks+8hi+t]
    short8 q[4];
    #pragma unroll
    for (int ks = 0; ks < 4; ++ks)
        q[ks] = *(const short8*)(Qb + (size_t)(i0w + l32) * CCH + ks * 16 + hi * 8);

    // hoisted per-lane LDS read bases; per-read addr = base ^ (slot<<4), slot=2ks+hi
    int gbase[2], kbase[2];
    #pragma unroll
    for (int jb = 0; jb < 2; ++jb)
        gbase[jb] = (jb * 32 + l32) * 128 + ((l32 & 7) << 4);
    #pragma unroll
    for (int cb = 0; cb < 2; ++cb)
        kbase[cb] = 8192 + (cb * 32 + l32) * 128 + ((l32 & 7) << 4);

    // hoisted per-lane staging source pointers (512 threads cover 8KB per half)
    const int srow = tid >> 3, scolb = (tid & 7) * 16;
    const char* gsrc = Gb + (size_t)(jlo + srow) * 128 + (scolb ^ ((srow & 7) << 4));
    const char* ksrc = Kb + (size_t)srow * 8192 + (size_t)jlo * 2 + (scolb ^ ((srow & 7) << 4));

    f32x16 zacc;
    #pragma unroll
    for (int r = 0; r < 16; ++r) zacc[r] = 0.f;

    f32x16 o[2];                         // [cb] O^T accumulators (32 rows x 64 ch)
    #pragma unroll
    for (int cb = 0; cb < 2; ++cb)
        #pragma unroll
        for (int r = 0; r < 16; ++r) o[cb][r] = 0.f;
    float ps = 0.f;                      // per-lane denominator partial (i = lane&31)

    auto STAGE = [&](int buf, int tt) {
        gload_lds16(gsrc + tt * (KVBLK * 128), lds[buf] + wave * 1024);
        gload_lds16(ksrc + tt * (KVBLK * 2),  lds[buf] + 8192 + wave * 1024);
    };

    STAGE(0, 0);
    __syncthreads();

    for (int t = 0; t < niter; ++t) {
        const int cur = t & 1;
        STAGE(cur ^ 1, (t + 1 < niter) ? t + 1 : 0);   // uniform (tail re-stages tile 0)
        const char* L = lds[cur];

        #pragma unroll
        for (int jb = 0; jb < 2; ++jb) {
            short8 ga[4];
            #pragma unroll
            for (int ks = 0; ks < 4; ++ks)
                ga[ks] = *(const short8*)(L + (gbase[jb] ^ ((2 * ks + hi) << 4)));

            __builtin_amdgcn_s_setprio(1);
            f32x16 acc = __builtin_amdgcn_mfma_f32_32x32x16_bf16(ga[0], q[0], zacc, 0, 0, 0);
            acc = __builtin_amdgcn_mfma_f32_32x32x16_bf16(ga[1], q[1], acc, 0, 0, 0);
            acc = __builtin_amdgcn_mfma_f32_32x32x16_bf16(ga[2], q[2], acc, 0, 0, 0);
            acc = __builtin_amdgcn_mfma_f32_32x32x16_bf16(ga[3], q[3], acc, 0, 0, 0);
            __builtin_amdgcn_s_setprio(0);

            float p[16];
            #pragma unroll
            for (int r = 0; r < 16; ++r) {
                p[r] = __builtin_amdgcn_exp2f(acc[r]);
                ps += p[r];
            }
            // pack: p[r] holds j_local=(r&3)+8*(r>>2)+4hi; PV B-frag needs
            // lane(hi) to hold j=16kk'+8hi+t. cvt_pk pairs + permlane32_swap (T12).
            short8 pf[2];
            #pragma unroll
            for (int kk = 0; kk < 2; ++kk) {
                unsigned int x0 = pack_bf16(p[8 * kk + 0], p[8 * kk + 1]);
                unsigned int x1 = pack_bf16(p[8 * kk + 2], p[8 * kk + 3]);
                unsigned int y0 = pack_bf16(p[8 * kk + 4], p[8 * kk + 5]);
                unsigned int y1 = pack_bf16(p[8 * kk + 6], p[8 * kk + 7]);
                asm("v_permlane32_swap_b32 %0, %1" : "+v"(x0), "+v"(y0));
                asm("v_permlane32_swap_b32 %0, %1" : "+v"(x1), "+v"(y1));
                union { unsigned int u[4]; short8 v; } w;
                w.u[0] = x0; w.u[1] = x1; w.u[2] = y0; w.u[3] = y1;
                pf[kk] = w.v;
            }

            // PV for this jb's two k-slices (ksg = 2jb+kk)
            __builtin_amdgcn_s_setprio(1);
            #pragma unroll
            for (int kk = 0; kk < 2; ++kk) {
                const int ksg = 2 * jb + kk;
                const short8 ka0 = *(const short8*)(L + (kbase[0] ^ ((2 * ksg + hi) << 4)));
                const short8 ka1 = *(const short8*)(L + (kbase[1] ^ ((2 * ksg + hi) << 4)));
                o[0] = __builtin_amdgcn_mfma_f32_32x32x16_bf16(ka0, pf[kk], o[0], 0, 0, 0);
                o[1] = __builtin_amdgcn_mfma_f32_32x32x16_bf16(ka1, pf[kk], o[1], 0, 0, 0);
            }
            __builtin_amdgcn_s_setprio(0);
        }
        __syncthreads();   // drains staging vmcnt + all waves done reading cur
    }

    // epilogue: O^T is channel-major -> coalesced bf16 stores
    const size_t pb = (size_t)(b * split + sp);
    #pragma unroll
    for (int cb = 0; cb < 2; ++cb)
        #pragma unroll
        for (int r = 0; r < 16; ++r) {
            const int c = cb * 32 + (r & 3) + 8 * (r >> 2) + 4 * hi;
            const int i = i0w + l32;
            Opart[(pb * CCH + c) * NPIX + i] = __float2bfloat16(o[cb][r]);
        }
    // combine hi-halves of the per-lane denominator partial
    ps += __shfl_xor(ps, 32);
    if (lane < 32)
        Lpart[pb * NPIX + i0w + l32] = ps;
}

// ---------------------------------------------------------------------------
// Kernel 3: combine, stripe form (R17-neutral, kept). Block = (b, 64-pixel
// stripe), all 64 channels. Lpart reduced once into LDS invL.
// ---------------------------------------------------------------------------
__global__ __launch_bounds__(256) void combine_kernel(
    const __hip_bfloat16* __restrict__ Opart, const float* __restrict__ Lpart,
    const float* __restrict__ x, float* __restrict__ out, int split)
{
    const int b  = blockIdx.x >> 6;
    const int i0 = (blockIdx.x & 63) << 6;

    __shared__ float invL[64];
    if (threadIdx.x < 64) {
        const int i = i0 + threadIdx.x;
        float L = 0.f;
        for (int s = 0; s < split; ++s)
            L += Lpart[((size_t)(b * split + s)) * NPIX + i];
        invL[threadIdx.x] = 1.0f / L;
    }
    __syncthreads();

    const int c    = threadIdx.x >> 2;        // 0..63
    const int ioff = (threadIdx.x & 3) * 16;  // 16 pixels per thread

    float acc[16];
    #pragma unroll
    for (int k = 0; k < 16; ++k) acc[k] = 0.f;

    for (int s = 0; s < split; ++s) {
        const size_t base = (((size_t)(b * split + s)) * CCH + c) * NPIX + i0 + ioff;
        const short8 v0 = *(const short8*)((const short*)Opart + base);
        const short8 v1 = *(const short8*)((const short*)Opart + base + 8);
        #pragma unroll
        for (int k = 0; k < 8; ++k) {
            union { unsigned int u; float f; } cv0, cv1;
            cv0.u = ((unsigned int)(unsigned short)v0[k]) << 16;
            cv1.u = ((unsigned int)(unsigned short)v1[k]) << 16;
            acc[k]     += cv0.f;
            acc[k + 8] += cv1.f;
        }
    }

    const size_t idx = ((size_t)b * CCH + c) * NPIX + i0 + ioff;
    #pragma unroll
    for (int kq = 0; kq < 4; ++kq) {
        const f32x4 xv = *(const f32x4*)&x[idx + 4 * kq];
        f32x4 r;
        #pragma unroll
        for (int t = 0; t < 4; ++t)
            r[t] = acc[kq * 4 + t] * invL[ioff + kq * 4 + t] + xv[t];
        *(f32x4*)&out[idx + 4 * kq] = r;
    }
}

extern "C" void kernel_launch(void* const* d_in, const int* in_sizes, int n_in,
                              void* d_out, int out_size, void* d_ws, size_t ws_size,
                              hipStream_t stream) {
    const float* x  = (const float*)d_in[0];
    const float* W1 = (const float*)d_in[1];
    const float* b1 = (const float*)d_in[2];
    const float* W2 = (const float*)d_in[3];
    const float* b2 = (const float*)d_in[4];
    const float* W3 = (const float*)d_in[5];
    const float* b3 = (const float*)d_in[6];
    float* out = (float*)d_out;

    char* ws = (char*)d_ws;
    const size_t planeB = (size_t)NB * NPIX * CCH * sizeof(__hip_bfloat16); // 4 MB
    __hip_bfloat16* Q = (__hip_bfloat16*)(ws);
    __hip_bfloat16* G = (__hip_bfloat16*)(ws + planeB);
    __hip_bfloat16* K = (__hip_bfloat16*)(ws + 2 * planeB);

    const size_t base   = 3 * planeB;                               // 12 MB
    const size_t oPlane = planeB;                                   // 4 MB per split (bf16)
    const size_t lPlane = (size_t)NB * NPIX * sizeof(float);        // 128 KB per split

    // prefer split=8 (1024 blocks = 4/CU); fall back if ws is tight
    int split = 8;
    while (split > 1 && base + (size_t)split * (oPlane + lPlane) > ws_size)
        split >>= 1;

    __hip_bfloat16* Opart = (__hip_bfloat16*)(ws + base);
    float* Lpart = (float*)(ws + base + (size_t)split * oPlane);

    proj_kernel<<<dim3(NB * 64 * 3), dim3(256), 0, stream>>>(x, W1, b1, W2, b2, W3, b3, Q, G, K);
    attn_kernel<<<dim3(NB * 16 * split), dim3(512), 0, stream>>>(Q, G, K, Opart, Lpart, split);
    combine_kernel<<<dim3(NB * 64), dim3(256), 0, stream>>>(Opart, Lpart, x, out, split);
}

// Round 20
// 73.272 us; speedup vs baseline: 3.6211x; 1.1319x over previous
//
#include <hip/hip_runtime.h>
#include <hip/hip_bf16.h>

#define NPIX 4096   // 64*64 pixels per batch
#define CCH  64     // channels
#define NB   8      // batch
#define KVBLK 64    // j-tile per pipeline stage (32KB LDS dbuf)

typedef __attribute__((ext_vector_type(8)))  short short8;   // 8 bf16 MFMA A/B frag (32x32x16)
typedef __attribute__((ext_vector_type(4)))  float f32x4;
typedef __attribute__((ext_vector_type(16))) float f32x16;   // 32x32 MFMA C/D frag

#define LOG2E   1.44269504f

__device__ __forceinline__ unsigned int pack_bf16(float lo, float hi) {
    union { __hip_bfloat162 h; unsigned int u; } w;
    w.h = __float22bfloat162_rn(make_float2(lo, hi));
    return w.u;
}

// ---------------------------------------------------------------------------
// Kernel 1: fused 1x1-conv projections via MFMA (R20).
// R14's vector-FMA version was the hidden tail hog: 805 MFLOP fp32 scalar FMA
// ~= 20us on the 157TF vector pipe. As bf16 MFMA it's ~0.3us of matrix-pipe
// time; kernel becomes staging/store-bound (~5us).
// Block = (b, 64-pixel tile), 4 waves. LDS: Xt[p][c] bf16 (pixel-major,
// 144B rows), Wb[m][oc][c] bf16, bsh[m][oc] f32. 12 output units =
// (3 matrices x 4 32x32 subtiles); wave w computes units w, w+4, w+8.
// 32x32x16 layouts (attn-proven): A row=lane&31 k=8hi+t (W), B col=lane&31
// k=8hi+t (Xt), D col=p row=(r&3)+8(r>>2)+4hi (oc).
//   m=0: Q[b][i][oc] = log2e * (W1 x + b1)   (bf16 pixel-major)
//   m=1: G[b][j][oc] =         (W2 x + b2)   (bf16 pixel-major)
//   m=2: K[b][oc][j] =         (W3 x + b3)   (bf16 channel-major)
// ---------------------------------------------------------------------------
__global__ __launch_bounds__(256) void proj_kernel(
    const float* __restrict__ x,
    const float* __restrict__ W1, const float* __restrict__ b1,
    const float* __restrict__ W2, const float* __restrict__ b2,
    const float* __restrict__ W3, const float* __restrict__ b3,
    __hip_bfloat16* __restrict__ Q, __hip_bfloat16* __restrict__ G,
    __hip_bfloat16* __restrict__ K)
{
    const int b    = blockIdx.x >> 6;
    const int i0   = (blockIdx.x & 63) << 6;
    const int tid  = threadIdx.x;
    const int wave = tid >> 6;
    const int lane = tid & 63;
    const int l32  = lane & 31;
    const int hi   = lane >> 5;

    __shared__ __hip_bfloat16 Xt[64][72];      // [p][c], 144B rows
    __shared__ __hip_bfloat16 Wb[3][64][64];   // [m][oc][c], 128B rows
    __shared__ float bsh[3][64];

    // x tile -> Xt (transpose to pixel-major bf16); coalesced f32x4 reads
    for (int e = tid; e < 1024; e += 256) {
        const int c = e >> 4, p4 = (e & 15) * 4;
        const f32x4 v = *(const f32x4*)&x[((size_t)b * CCH + c) * NPIX + i0 + p4];
        #pragma unroll
        for (int t = 0; t < 4; ++t)
            Xt[p4 + t][c] = __float2bfloat16(v[t]);
    }
    // W matrices -> Wb bf16 (packed dword writes)
    #pragma unroll
    for (int m = 0; m < 3; ++m) {
        const float* W = (m == 0) ? W1 : (m == 1) ? W2 : W3;
        for (int e = tid; e < 1024; e += 256) {
            const int oc = e >> 4, c4 = (e & 15) * 4;
            const f32x4 v = *(const f32x4*)&W[oc * 64 + c4];
            *(unsigned int*)&Wb[m][oc][c4]     = pack_bf16(v[0], v[1]);
            *(unsigned int*)&Wb[m][oc][c4 + 2] = pack_bf16(v[2], v[3]);
        }
    }
    if (tid < 192) {
        const int m = tid >> 6, oc = tid & 63;
        bsh[m][oc] = ((m == 0) ? b1 : (m == 1) ? b2 : b3)[oc];
    }
    __syncthreads();

    #pragma unroll
    for (int u = 0; u < 3; ++u) {
        const int unit = wave + 4 * u;           // 0..11
        const int m  = unit >> 2;                // matrix
        const int sr = (unit >> 1) & 1;          // oc subtile
        const int sc = unit & 1;                 // pixel subtile

        f32x16 acc;
        #pragma unroll
        for (int r = 0; r < 16; ++r) {
            const int oc = sr * 32 + (r & 3) + 8 * (r >> 2) + 4 * hi;
            acc[r] = bsh[m][oc];
        }
        #pragma unroll
        for (int ks = 0; ks < 4; ++ks) {
            const short8 af = *(const short8*)&Wb[m][sr * 32 + l32][ks * 16 + hi * 8];
            const short8 bf = *(const short8*)&Xt[sc * 32 + l32][ks * 16 + hi * 8];
            acc = __builtin_amdgcn_mfma_f32_32x32x16_bf16(af, bf, acc, 0, 0, 0);
        }

        const int i = i0 + sc * 32 + l32;
        if (m == 0) {
            #pragma unroll
            for (int r = 0; r < 16; ++r) {
                const int oc = sr * 32 + (r & 3) + 8 * (r >> 2) + 4 * hi;
                Q[((size_t)b * NPIX + i) * CCH + oc] = __float2bfloat16(acc[r] * LOG2E);
            }
        } else if (m == 1) {
            #pragma unroll
            for (int r = 0; r < 16; ++r) {
                const int oc = sr * 32 + (r & 3) + 8 * (r >> 2) + 4 * hi;
                G[((size_t)b * NPIX + i) * CCH + oc] = __float2bfloat16(acc[r]);
            }
        } else {
            #pragma unroll
            for (int r = 0; r < 16; ++r) {
                const int oc = sr * 32 + (r & 3) + 8 * (r >> 2) + 4 * hi;
                K[((size_t)b * CCH + oc) * NPIX + i] = __float2bfloat16(acc[r]);
            }
        }
    }
}

// ---------------------------------------------------------------------------
// Kernel 2: LDS-staged flash attention — R14/R19-proven best (48.5us, VGPR 52).
// 8 waves x 32 rows (512 threads), 4 waves/SIMD. KVBLK=64 dbuf+syncthreads.
// Byte-identical to R19.
// ---------------------------------------------------------------------------
__device__ __forceinline__ void gload_lds16(const void* g, void* l) {
    __builtin_amdgcn_global_load_lds(
        (const __attribute__((address_space(1))) unsigned int*)g,
        (__attribute__((address_space(3))) unsigned int*)l, 16, 0, 0);
}

__global__ __launch_bounds__(512, 4) void attn_kernel(
    const __hip_bfloat16* __restrict__ Qg, const __hip_bfloat16* __restrict__ Gg,
    const __hip_bfloat16* __restrict__ Kg,
    __hip_bfloat16* __restrict__ Opart, float* __restrict__ Lpart, int split)
{
    __shared__ char lds[2][16384];      // [buf][ G 8KB | K 8KB ], XOR-swizzled

    const int blk   = blockIdx.x;
    const int per_b = 16 * split;
    const int b     = blk / per_b;
    const int rem   = blk - b * per_b;
    const int itile = rem / split;
    const int sp    = rem - itile * split;
    const int tid   = threadIdx.x;
    const int wave  = tid >> 6;                   // 0..7
    const int lane  = tid & 63;
    const int l32   = lane & 31;
    const int hi    = lane >> 5;
    const int i0w   = itile * 256 + wave * 32;    // wave's first of 32 rows
    const int jcnt  = NPIX / split;
    const int jlo   = sp * jcnt;
    const int niter = jcnt / KVBLK;

    const short* Qb = (const short*)Qg + (size_t)b * NPIX * CCH;
    const char*  Gb = (const char*)(Gg + (size_t)b * NPIX * CCH);
    const char*  Kb = (const char*)(Kg + (size_t)b * CCH * NPIX);

    // Q B-frags: q[ks] -> Q[i0w+l32][16ks+8hi+t]
    short8 q[4];
    #pragma unroll
    for (int ks = 0; ks < 4; ++ks)
        q[ks] = *(const short8*)(Qb + (size_t)(i0w + l32) * CCH + ks * 16 + hi * 8);

    // hoisted per-lane LDS read bases; per-read addr = base ^ (slot<<4), slot=2ks+hi
    int gbase[2], kbase[2];
    #pragma unroll
    for (int jb = 0; jb < 2; ++jb)
        gbase[jb] = (jb * 32 + l32) * 128 + ((l32 & 7) << 4);
    #pragma unroll
    for (int cb = 0; cb < 2; ++cb)
        kbase[cb] = 8192 + (cb * 32 + l32) * 128 + ((l32 & 7) << 4);

    // hoisted per-lane staging source pointers (512 threads cover 8KB per half)
    const int srow = tid >> 3, scolb = (tid & 7) * 16;
    const char* gsrc = Gb + (size_t)(jlo + srow) * 128 + (scolb ^ ((srow & 7) << 4));
    const char* ksrc = Kb + (size_t)srow * 8192 + (size_t)jlo * 2 + (scolb ^ ((srow & 7) << 4));

    f32x16 zacc;
    #pragma unroll
    for (int r = 0; r < 16; ++r) zacc[r] = 0.f;

    f32x16 o[2];                         // [cb] O^T accumulators (32 rows x 64 ch)
    #pragma unroll
    for (int cb = 0; cb < 2; ++cb)
        #pragma unroll
        for (int r = 0; r < 16; ++r) o[cb][r] = 0.f;
    float ps = 0.f;                      // per-lane denominator partial (i = lane&31)

    auto STAGE = [&](int buf, int tt) {
        gload_lds16(gsrc + tt * (KVBLK * 128), lds[buf] + wave * 1024);
        gload_lds16(ksrc + tt * (KVBLK * 2),  lds[buf] + 8192 + wave * 1024);
    };

    STAGE(0, 0);
    __syncthreads();

    for (int t = 0; t < niter; ++t) {
        const int cur = t & 1;
        STAGE(cur ^ 1, (t + 1 < niter) ? t + 1 : 0);   // uniform (tail re-stages tile 0)
        const char* L = lds[cur];

        #pragma unroll
        for (int jb = 0; jb < 2; ++jb) {
            short8 ga[4];
            #pragma unroll
            for (int ks = 0; ks < 4; ++ks)
                ga[ks] = *(const short8*)(L + (gbase[jb] ^ ((2 * ks + hi) << 4)));

            __builtin_amdgcn_s_setprio(1);
            f32x16 acc = __builtin_amdgcn_mfma_f32_32x32x16_bf16(ga[0], q[0], zacc, 0, 0, 0);
            acc = __builtin_amdgcn_mfma_f32_32x32x16_bf16(ga[1], q[1], acc, 0, 0, 0);
            acc = __builtin_amdgcn_mfma_f32_32x32x16_bf16(ga[2], q[2], acc, 0, 0, 0);
            acc = __builtin_amdgcn_mfma_f32_32x32x16_bf16(ga[3], q[3], acc, 0, 0, 0);
            __builtin_amdgcn_s_setprio(0);

            float p[16];
            #pragma unroll
            for (int r = 0; r < 16; ++r) {
                p[r] = __builtin_amdgcn_exp2f(acc[r]);
                ps += p[r];
            }
            // pack: p[r] holds j_local=(r&3)+8*(r>>2)+4hi; PV B-frag needs
            // lane(hi) to hold j=16kk'+8hi+t. cvt_pk pairs + permlane32_swap (T12).
            short8 pf[2];
            #pragma unroll
            for (int kk = 0; kk < 2; ++kk) {
                unsigned int x0 = pack_bf16(p[8 * kk + 0], p[8 * kk + 1]);
                unsigned int x1 = pack_bf16(p[8 * kk + 2], p[8 * kk + 3]);
                unsigned int y0 = pack_bf16(p[8 * kk + 4], p[8 * kk + 5]);
                unsigned int y1 = pack_bf16(p[8 * kk + 6], p[8 * kk + 7]);
                asm("v_permlane32_swap_b32 %0, %1" : "+v"(x0), "+v"(y0));
                asm("v_permlane32_swap_b32 %0, %1" : "+v"(x1), "+v"(y1));
                union { unsigned int u[4]; short8 v; } w;
                w.u[0] = x0; w.u[1] = x1; w.u[2] = y0; w.u[3] = y1;
                pf[kk] = w.v;
            }

            // PV for this jb's two k-slices (ksg = 2jb+kk)
            __builtin_amdgcn_s_setprio(1);
            #pragma unroll
            for (int kk = 0; kk < 2; ++kk) {
                const int ksg = 2 * jb + kk;
                const short8 ka0 = *(const short8*)(L + (kbase[0] ^ ((2 * ksg + hi) << 4)));
                const short8 ka1 = *(const short8*)(L + (kbase[1] ^ ((2 * ksg + hi) << 4)));
                o[0] = __builtin_amdgcn_mfma_f32_32x32x16_bf16(ka0, pf[kk], o[0], 0, 0, 0);
                o[1] = __builtin_amdgcn_mfma_f32_32x32x16_bf16(ka1, pf[kk], o[1], 0, 0, 0);
            }
            __builtin_amdgcn_s_setprio(0);
        }
        __syncthreads();   // drains staging vmcnt + all waves done reading cur
    }

    // epilogue: O^T is channel-major -> coalesced bf16 stores
    const size_t pb = (size_t)(b * split + sp);
    #pragma unroll
    for (int cb = 0; cb < 2; ++cb)
        #pragma unroll
        for (int r = 0; r < 16; ++r) {
            const int c = cb * 32 + (r & 3) + 8 * (r >> 2) + 4 * hi;
            const int i = i0w + l32;
            Opart[(pb * CCH + c) * NPIX + i] = __float2bfloat16(o[cb][r]);
        }
    // combine hi-halves of the per-lane denominator partial
    ps += __shfl_xor(ps, 32);
    if (lane < 32)
        Lpart[pb * NPIX + i0w + l32] = ps;
}

// ---------------------------------------------------------------------------
// Kernel 3: combine, stripe form (R17/R19). Block = (b, 64-pixel stripe),
// all 64 channels. Lpart reduced once into LDS invL. Byte-identical to R19.
// ---------------------------------------------------------------------------
__global__ __launch_bounds__(256) void combine_kernel(
    const __hip_bfloat16* __restrict__ Opart, const float* __restrict__ Lpart,
    const float* __restrict__ x, float* __restrict__ out, int split)
{
    const int b  = blockIdx.x >> 6;
    const int i0 = (blockIdx.x & 63) << 6;

    __shared__ float invL[64];
    if (threadIdx.x < 64) {
        const int i = i0 + threadIdx.x;
        float L = 0.f;
        for (int s = 0; s < split; ++s)
            L += Lpart[((size_t)(b * split + s)) * NPIX + i];
        invL[threadIdx.x] = 1.0f / L;
    }
    __syncthreads();

    const int c    = threadIdx.x >> 2;        // 0..63
    const int ioff = (threadIdx.x & 3) * 16;  // 16 pixels per thread

    float acc[16];
    #pragma unroll
    for (int k = 0; k < 16; ++k) acc[k] = 0.f;

    for (int s = 0; s < split; ++s) {
        const size_t base = (((size_t)(b * split + s)) * CCH + c) * NPIX + i0 + ioff;
        const short8 v0 = *(const short8*)((const short*)Opart + base);
        const short8 v1 = *(const short8*)((const short*)Opart + base + 8);
        #pragma unroll
        for (int k = 0; k < 8; ++k) {
            union { unsigned int u; float f; } cv0, cv1;
            cv0.u = ((unsigned int)(unsigned short)v0[k]) << 16;
            cv1.u = ((unsigned int)(unsigned short)v1[k]) << 16;
            acc[k]     += cv0.f;
            acc[k + 8] += cv1.f;
        }
    }

    const size_t idx = ((size_t)b * CCH + c) * NPIX + i0 + ioff;
    #pragma unroll
    for (int kq = 0; kq < 4; ++kq) {
        const f32x4 xv = *(const f32x4*)&x[idx + 4 * kq];
        f32x4 r;
        #pragma unroll
        for (int t = 0; t < 4; ++t)
            r[t] = acc[kq * 4 + t] * invL[ioff + kq * 4 + t] + xv[t];
        *(f32x4*)&out[idx + 4 * kq] = r;
    }
}

extern "C" void kernel_launch(void* const* d_in, const int* in_sizes, int n_in,
                              void* d_out, int out_size, void* d_ws, size_t ws_size,
                              hipStream_t stream) {
    const float* x  = (const float*)d_in[0];
    const float* W1 = (const float*)d_in[1];
    const float* b1 = (const float*)d_in[2];
    const float* W2 = (const float*)d_in[3];
    const float* b2 = (const float*)d_in[4];
    const float* W3 = (const float*)d_in[5];
    const float* b3 = (const float*)d_in[6];
    float* out = (float*)d_out;

    char* ws = (char*)d_ws;
    const size_t planeB = (size_t)NB * NPIX * CCH * sizeof(__hip_bfloat16); // 4 MB
    __hip_bfloat16* Q = (__hip_bfloat16*)(ws);
    __hip_bfloat16* G = (__hip_bfloat16*)(ws + planeB);
    __hip_bfloat16* K = (__hip_bfloat16*)(ws + 2 * planeB);

    const size_t base   = 3 * planeB;                               // 12 MB
    const size_t oPlane = planeB;                                   // 4 MB per split (bf16)
    const size_t lPlane = (size_t)NB * NPIX * sizeof(float);        // 128 KB per split

    // prefer split=8 (1024 blocks = 4/CU); fall back if ws is tight
    int split = 8;
    while (split > 1 && base + (size_t)split * (oPlane + lPlane) > ws_size)
        split >>= 1;

    __hip_bfloat16* Opart = (__hip_bfloat16*)(ws + base);
    float* Lpart = (float*)(ws + base + (size_t)split * oPlane);

    proj_kernel<<<dim3(NB * 64), dim3(256), 0, stream>>>(x, W1, b1, W2, b2, W3, b3, Q, G, K);
    attn_kernel<<<dim3(NB * 16 * split), dim3(512), 0, stream>>>(Q, G, K, Opart, Lpart, split);
    combine_kernel<<<dim3(NB * 64), dim3(256), 0, stream>>>(Opart, Lpart, x, out, split);
}

// Round 21
// 72.826 us; speedup vs baseline: 3.6433x; 1.0061x over previous
//
#include <hip/hip_runtime.h>
#include <hip/hip_bf16.h>

#define NPIX 4096   // 64*64 pixels per batch
#define CCH  64     // channels
#define NB   8      // batch
#define KVBLK 64    // j-tile per pipeline stage (32KB LDS dbuf)

typedef __attribute__((ext_vector_type(8)))  short short8;   // 8 bf16 MFMA A/B frag (32x32x16)
typedef __attribute__((ext_vector_type(4)))  float f32x4;
typedef __attribute__((ext_vector_type(16))) float f32x16;   // 32x32 MFMA C/D frag

#define LOG2E   1.44269504f

__device__ __forceinline__ unsigned int pack_bf16(float lo, float hi) {
    union { __hip_bfloat162 h; unsigned int u; } w;
    w.h = __float22bfloat162_rn(make_float2(lo, hi));
    return w.u;
}

// ---------------------------------------------------------------------------
// Kernel 1: fused 1x1-conv projections via MFMA (R20-proven, -9.6us vs fp32).
// Block = (b, 64-pixel tile), 4 waves; 12 (matrix x 32x32-subtile) units.
// ---------------------------------------------------------------------------
__global__ __launch_bounds__(256) void proj_kernel(
    const float* __restrict__ x,
    const float* __restrict__ W1, const float* __restrict__ b1,
    const float* __restrict__ W2, const float* __restrict__ b2,
    const float* __restrict__ W3, const float* __restrict__ b3,
    __hip_bfloat16* __restrict__ Q, __hip_bfloat16* __restrict__ G,
    __hip_bfloat16* __restrict__ K)
{
    const int b    = blockIdx.x >> 6;
    const int i0   = (blockIdx.x & 63) << 6;
    const int tid  = threadIdx.x;
    const int wave = tid >> 6;
    const int lane = tid & 63;
    const int l32  = lane & 31;
    const int hi   = lane >> 5;

    __shared__ __hip_bfloat16 Xt[64][72];      // [p][c], 144B rows
    __shared__ __hip_bfloat16 Wb[3][64][64];   // [m][oc][c], 128B rows
    __shared__ float bsh[3][64];

    for (int e = tid; e < 1024; e += 256) {
        const int c = e >> 4, p4 = (e & 15) * 4;
        const f32x4 v = *(const f32x4*)&x[((size_t)b * CCH + c) * NPIX + i0 + p4];
        #pragma unroll
        for (int t = 0; t < 4; ++t)
            Xt[p4 + t][c] = __float2bfloat16(v[t]);
    }
    #pragma unroll
    for (int m = 0; m < 3; ++m) {
        const float* W = (m == 0) ? W1 : (m == 1) ? W2 : W3;
        for (int e = tid; e < 1024; e += 256) {
            const int oc = e >> 4, c4 = (e & 15) * 4;
            const f32x4 v = *(const f32x4*)&W[oc * 64 + c4];
            *(unsigned int*)&Wb[m][oc][c4]     = pack_bf16(v[0], v[1]);
            *(unsigned int*)&Wb[m][oc][c4 + 2] = pack_bf16(v[2], v[3]);
        }
    }
    if (tid < 192) {
        const int m = tid >> 6, oc = tid & 63;
        bsh[m][oc] = ((m == 0) ? b1 : (m == 1) ? b2 : b3)[oc];
    }
    __syncthreads();

    #pragma unroll
    for (int u = 0; u < 3; ++u) {
        const int unit = wave + 4 * u;           // 0..11
        const int m  = unit >> 2;                // matrix
        const int sr = (unit >> 1) & 1;          // oc subtile
        const int sc = unit & 1;                 // pixel subtile

        f32x16 acc;
        #pragma unroll
        for (int r = 0; r < 16; ++r) {
            const int oc = sr * 32 + (r & 3) + 8 * (r >> 2) + 4 * hi;
            acc[r] = bsh[m][oc];
        }
        #pragma unroll
        for (int ks = 0; ks < 4; ++ks) {
            const short8 af = *(const short8*)&Wb[m][sr * 32 + l32][ks * 16 + hi * 8];
            const short8 bf = *(const short8*)&Xt[sc * 32 + l32][ks * 16 + hi * 8];
            acc = __builtin_amdgcn_mfma_f32_32x32x16_bf16(af, bf, acc, 0, 0, 0);
        }

        const int i = i0 + sc * 32 + l32;
        if (m == 0) {
            #pragma unroll
            for (int r = 0; r < 16; ++r) {
                const int oc = sr * 32 + (r & 3) + 8 * (r >> 2) + 4 * hi;
                Q[((size_t)b * NPIX + i) * CCH + oc] = __float2bfloat16(acc[r] * LOG2E);
            }
        } else if (m == 1) {
            #pragma unroll
            for (int r = 0; r < 16; ++r) {
                const int oc = sr * 32 + (r & 3) + 8 * (r >> 2) + 4 * hi;
                G[((size_t)b * NPIX + i) * CCH + oc] = __float2bfloat16(acc[r]);
            }
        } else {
            #pragma unroll
            for (int r = 0; r < 16; ++r) {
                const int oc = sr * 32 + (r & 3) + 8 * (r >> 2) + 4 * hi;
                K[((size_t)b * CCH + oc) * NPIX + i] = __float2bfloat16(acc[r]);
            }
        }
    }
}

// ---------------------------------------------------------------------------
// Kernel 2: LDS-staged flash attention — R14/R19 base (48.5us, VGPR 52).
// R21 delta: wave-parity jb STAGGER — odd waves process jb sub-tiles in
// reverse order (jb = jj ^ (wave&1)). De-phases the per-barrier LDS-read
// storm vs MFMA/exp phase across waves (measured: LDS ~27us + VALU ~26us on
// separate pipes, wall ~= sum -> alternation, not overlap). Pure reorder of
// commutative accumulations; everything else byte-identical to R20.
// ---------------------------------------------------------------------------
__device__ __forceinline__ void gload_lds16(const void* g, void* l) {
    __builtin_amdgcn_global_load_lds(
        (const __attribute__((address_space(1))) unsigned int*)g,
        (__attribute__((address_space(3))) unsigned int*)l, 16, 0, 0);
}

__global__ __launch_bounds__(512, 4) void attn_kernel(
    const __hip_bfloat16* __restrict__ Qg, const __hip_bfloat16* __restrict__ Gg,
    const __hip_bfloat16* __restrict__ Kg,
    __hip_bfloat16* __restrict__ Opart, float* __restrict__ Lpart, int split)
{
    __shared__ char lds[2][16384];      // [buf][ G 8KB | K 8KB ], XOR-swizzled

    const int blk   = blockIdx.x;
    const int per_b = 16 * split;
    const int b     = blk / per_b;
    const int rem   = blk - b * per_b;
    const int itile = rem / split;
    const int sp    = rem - itile * split;
    const int tid   = threadIdx.x;
    const int wave  = tid >> 6;                   // 0..7
    const int lane  = tid & 63;
    const int l32   = lane & 31;
    const int hi    = lane >> 5;
    const int i0w   = itile * 256 + wave * 32;    // wave's first of 32 rows
    const int jcnt  = NPIX / split;
    const int jlo   = sp * jcnt;
    const int niter = jcnt / KVBLK;

    const short* Qb = (const short*)Qg + (size_t)b * NPIX * CCH;
    const char*  Gb = (const char*)(Gg + (size_t)b * NPIX * CCH);
    const char*  Kb = (const char*)(Kg + (size_t)b * CCH * NPIX);

    // Q B-frags: q[ks] -> Q[i0w+l32][16ks+8hi+t]
    short8 q[4];
    #pragma unroll
    for (int ks = 0; ks < 4; ++ks)
        q[ks] = *(const short8*)(Qb + (size_t)(i0w + l32) * CCH + ks * 16 + hi * 8);

    // hoisted per-lane LDS read bases; per-read addr = base ^ (slot<<4), slot=2ks+hi
    int gbase[2], kbase[2];
    #pragma unroll
    for (int jb = 0; jb < 2; ++jb)
        gbase[jb] = (jb * 32 + l32) * 128 + ((l32 & 7) << 4);
    #pragma unroll
    for (int cb = 0; cb < 2; ++cb)
        kbase[cb] = 8192 + (cb * 32 + l32) * 128 + ((l32 & 7) << 4);

    // hoisted per-lane staging source pointers (512 threads cover 8KB per half)
    const int srow = tid >> 3, scolb = (tid & 7) * 16;
    const char* gsrc = Gb + (size_t)(jlo + srow) * 128 + (scolb ^ ((srow & 7) << 4));
    const char* ksrc = Kb + (size_t)srow * 8192 + (size_t)jlo * 2 + (scolb ^ ((srow & 7) << 4));

    f32x16 zacc;
    #pragma unroll
    for (int r = 0; r < 16; ++r) zacc[r] = 0.f;

    f32x16 o[2];                         // [cb] O^T accumulators (32 rows x 64 ch)
    #pragma unroll
    for (int cb = 0; cb < 2; ++cb)
        #pragma unroll
        for (int r = 0; r < 16; ++r) o[cb][r] = 0.f;
    float ps = 0.f;                      // per-lane denominator partial (i = lane&31)

    auto STAGE = [&](int buf, int tt) {
        gload_lds16(gsrc + tt * (KVBLK * 128), lds[buf] + wave * 1024);
        gload_lds16(ksrc + tt * (KVBLK * 2),  lds[buf] + 8192 + wave * 1024);
    };

    STAGE(0, 0);
    __syncthreads();

    const int wpar = wave & 1;           // phase-stagger parity

    for (int t = 0; t < niter; ++t) {
        const int cur = t & 1;
        STAGE(cur ^ 1, (t + 1 < niter) ? t + 1 : 0);   // uniform (tail re-stages tile 0)
        const char* L = lds[cur];

        #pragma unroll
        for (int jj = 0; jj < 2; ++jj) {
            const int jb = jj ^ wpar;    // odd waves: jb order 1,0 -> de-phased pipes
            short8 ga[4];
            #pragma unroll
            for (int ks = 0; ks < 4; ++ks)
                ga[ks] = *(const short8*)(L + (gbase[jb] ^ ((2 * ks + hi) << 4)));

            __builtin_amdgcn_s_setprio(1);
            f32x16 acc = __builtin_amdgcn_mfma_f32_32x32x16_bf16(ga[0], q[0], zacc, 0, 0, 0);
            acc = __builtin_amdgcn_mfma_f32_32x32x16_bf16(ga[1], q[1], acc, 0, 0, 0);
            acc = __builtin_amdgcn_mfma_f32_32x32x16_bf16(ga[2], q[2], acc, 0, 0, 0);
            acc = __builtin_amdgcn_mfma_f32_32x32x16_bf16(ga[3], q[3], acc, 0, 0, 0);
            __builtin_amdgcn_s_setprio(0);

            float p[16];
            #pragma unroll
            for (int r = 0; r < 16; ++r) {
                p[r] = __builtin_amdgcn_exp2f(acc[r]);
                ps += p[r];
            }
            // pack: p[r] holds j_local=(r&3)+8*(r>>2)+4hi; PV B-frag needs
            // lane(hi) to hold j=16kk'+8hi+t. cvt_pk pairs + permlane32_swap (T12).
            short8 pf[2];
            #pragma unroll
            for (int kk = 0; kk < 2; ++kk) {
                unsigned int x0 = pack_bf16(p[8 * kk + 0], p[8 * kk + 1]);
                unsigned int x1 = pack_bf16(p[8 * kk + 2], p[8 * kk + 3]);
                unsigned int y0 = pack_bf16(p[8 * kk + 4], p[8 * kk + 5]);
                unsigned int y1 = pack_bf16(p[8 * kk + 6], p[8 * kk + 7]);
                asm("v_permlane32_swap_b32 %0, %1" : "+v"(x0), "+v"(y0));
                asm("v_permlane32_swap_b32 %0, %1" : "+v"(x1), "+v"(y1));
                union { unsigned int u[4]; short8 v; } w;
                w.u[0] = x0; w.u[1] = x1; w.u[2] = y0; w.u[3] = y1;
                pf[kk] = w.v;
            }

            // PV for this jb's two k-slices (ksg = 2jb+kk)
            __builtin_amdgcn_s_setprio(1);
            #pragma unroll
            for (int kk = 0; kk < 2; ++kk) {
                const int ksg = 2 * jb + kk;
                const short8 ka0 = *(const short8*)(L + (kbase[0] ^ ((2 * ksg + hi) << 4)));
                const short8 ka1 = *(const short8*)(L + (kbase[1] ^ ((2 * ksg + hi) << 4)));
                o[0] = __builtin_amdgcn_mfma_f32_32x32x16_bf16(ka0, pf[kk], o[0], 0, 0, 0);
                o[1] = __builtin_amdgcn_mfma_f32_32x32x16_bf16(ka1, pf[kk], o[1], 0, 0, 0);
            }
            __builtin_amdgcn_s_setprio(0);
        }
        __syncthreads();   // drains staging vmcnt + all waves done reading cur
    }

    // epilogue: O^T is channel-major -> coalesced bf16 stores
    const size_t pb = (size_t)(b * split + sp);
    #pragma unroll
    for (int cb = 0; cb < 2; ++cb)
        #pragma unroll
        for (int r = 0; r < 16; ++r) {
            const int c = cb * 32 + (r & 3) + 8 * (r >> 2) + 4 * hi;
            const int i = i0w + l32;
            Opart[(pb * CCH + c) * NPIX + i] = __float2bfloat16(o[cb][r]);
        }
    // combine hi-halves of the per-lane denominator partial
    ps += __shfl_xor(ps, 32);
    if (lane < 32)
        Lpart[pb * NPIX + i0w + l32] = ps;
}

// ---------------------------------------------------------------------------
// Kernel 3: combine, stripe form (R17/R19). Block = (b, 64-pixel stripe),
// all 64 channels. Lpart reduced once into LDS invL. Byte-identical to R20.
// ---------------------------------------------------------------------------
__global__ __launch_bounds__(256) void combine_kernel(
    const __hip_bfloat16* __restrict__ Opart, const float* __restrict__ Lpart,
    const float* __restrict__ x, float* __restrict__ out, int split)
{
    const int b  = blockIdx.x >> 6;
    const int i0 = (blockIdx.x & 63) << 6;

    __shared__ float invL[64];
    if (threadIdx.x < 64) {
        const int i = i0 + threadIdx.x;
        float L = 0.f;
        for (int s = 0; s < split; ++s)
            L += Lpart[((size_t)(b * split + s)) * NPIX + i];
        invL[threadIdx.x] = 1.0f / L;
    }
    __syncthreads();

    const int c    = threadIdx.x >> 2;        // 0..63
    const int ioff = (threadIdx.x & 3) * 16;  // 16 pixels per thread

    float acc[16];
    #pragma unroll
    for (int k = 0; k < 16; ++k) acc[k] = 0.f;

    for (int s = 0; s < split; ++s) {
        const size_t base = (((size_t)(b * split + s)) * CCH + c) * NPIX + i0 + ioff;
        const short8 v0 = *(const short8*)((const short*)Opart + base);
        const short8 v1 = *(const short8*)((const short*)Opart + base + 8);
        #pragma unroll
        for (int k = 0; k < 8; ++k) {
            union { unsigned int u; float f; } cv0, cv1;
            cv0.u = ((unsigned int)(unsigned short)v0[k]) << 16;
            cv1.u = ((unsigned int)(unsigned short)v1[k]) << 16;
            acc[k]     += cv0.f;
            acc[k + 8] += cv1.f;
        }
    }

    const size_t idx = ((size_t)b * CCH + c) * NPIX + i0 + ioff;
    #pragma unroll
    for (int kq = 0; kq < 4; ++kq) {
        const f32x4 xv = *(const f32x4*)&x[idx + 4 * kq];
        f32x4 r;
        #pragma unroll
        for (int t = 0; t < 4; ++t)
            r[t] = acc[kq * 4 + t] * invL[ioff + kq * 4 + t] + xv[t];
        *(f32x4*)&out[idx + 4 * kq] = r;
    }
}

extern "C" void kernel_launch(void* const* d_in, const int* in_sizes, int n_in,
                              void* d_out, int out_size, void* d_ws, size_t ws_size,
                              hipStream_t stream) {
    const float* x  = (const float*)d_in[0];
    const float* W1 = (const float*)d_in[1];
    const float* b1 = (const float*)d_in[2];
    const float* W2 = (const float*)d_in[3];
    const float* b2 = (const float*)d_in[4];
    const float* W3 = (const float*)d_in[5];
    const float* b3 = (const float*)d_in[6];
    float* out = (float*)d_out;

    char* ws = (char*)d_ws;
    const size_t planeB = (size_t)NB * NPIX * CCH * sizeof(__hip_bfloat16); // 4 MB
    __hip_bfloat16* Q = (__hip_bfloat16*)(ws);
    __hip_bfloat16* G = (__hip_bfloat16*)(ws + planeB);
    __hip_bfloat16* K = (__hip_bfloat16*)(ws + 2 * planeB);

    const size_t base   = 3 * planeB;                               // 12 MB
    const size_t oPlane = planeB;                                   // 4 MB per split (bf16)
    const size_t lPlane = (size_t)NB * NPIX * sizeof(float);        // 128 KB per split

    // prefer split=8 (1024 blocks = 4/CU); fall back if ws is tight
    int split = 8;
    while (split > 1 && base + (size_t)split * (oPlane + lPlane) > ws_size)
        split >>= 1;

    __hip_bfloat16* Opart = (__hip_bfloat16*)(ws + base);
    float* Lpart = (float*)(ws + base + (size_t)split * oPlane);

    proj_kernel<<<dim3(NB * 64), dim3(256), 0, stream>>>(x, W1, b1, W2, b2, W3, b3, Q, G, K);
    attn_kernel<<<dim3(NB * 16 * split), dim3(512), 0, stream>>>(Q, G, K, Opart, Lpart, split);
    combine_kernel<<<dim3(NB * 64), dim3(256), 0, stream>>>(Opart, Lpart, x, out, split);
}